// Round 7
// baseline (267.388 us; speedup 1.0000x reference)
//
#include <hip/hip_runtime.h>
#include <hip/hip_cooperative_groups.h>
#include <cstdint>
#include <cstddef>

namespace cg = cooperative_groups;

typedef float f4 __attribute__((ext_vector_type(4)));

// Problem constants (match reference setup_inputs)
constexpr int Bn  = 32;
constexpr int Hh  = 512;
constexpr int Ww  = 512;
constexpr int Kb  = 9;
constexpr float EPS_MAG_F = 1e-6f;
constexpr float EPS_IN_F  = 1e-5f;
constexpr float LOG2E_F   = 1.4426950408889634f;

#if __has_builtin(__builtin_amdgcn_exp2f)
#define EXP2F(x) __builtin_amdgcn_exp2f(x)
#else
#define EXP2F(x) exp2f(x)
#endif
#if __has_builtin(__builtin_amdgcn_sqrtf)
#define SQRTF(x) __builtin_amdgcn_sqrtf(x)
#else
#define SQRTF(x) sqrtf(x)
#endif
#if __has_builtin(__builtin_amdgcn_rcpf)
#define RCPF(x) __builtin_amdgcn_rcpf(x)
#else
#define RCPF(x) (1.0f / (x))
#endif

struct RowW { float hd[4]; float hs[4]; };

// ============================================================================
// FUSED cooperative kernel: 1024 blocks (32 img x 32 chunks), 256 thr, 4/CU.
// Phase A: stage channel-summed 18x512 tile in LDS, per-block stat partials.
// grid sync. Phase B: reduce stats (redundant per block, deterministic),
// recompute from resident LDS, NT-write output (pure write stream).
// ============================================================================
constexpr int FTH     = 16;
constexpr int FCHUNKS = Hh / FTH;            // 32
constexpr int FLDS_H  = FTH + 2;             // 18

__global__ __launch_bounds__(256, 4) void goe_fused_kernel(
    const float* __restrict__ x,         // [B,3,H,W]
    const float* __restrict__ orient_w,  // [9,2]
    const float* __restrict__ gamma,     // [9]
    const float* __restrict__ beta,      // [9]
    float* __restrict__ partial,         // [32*32*18]
    float* __restrict__ out)             // [B,9,H,W]
{
    __shared__ float sm[FLDS_H][Ww];     // 36.9 KB, persists across grid sync
    __shared__ float red2[FCHUNKS * 18]; // 2.3 KB
    __shared__ float sums[18];
    __shared__ float2 stsh[Kb];

    const int bx    = blockIdx.x;
    const int b     = bx >> 5;           // /FCHUNKS
    const int chunk = bx & (FCHUNKS - 1);
    const int h0    = chunk * FTH;
    const int tid   = threadIdx.x;       // 0..255
    const int tx    = tid & 127;
    const int ty    = tid >> 7;
    const int lane  = tid & 63;

    const size_t plane = (size_t)Hh * Ww;
    const float* xb = x + (size_t)b * 3 * plane;

    // ---- stage channel-summed 18x512 tile (zero-padded top/bottom rows) ----
#pragma unroll
    for (int it = 0; it < 9; ++it) {
        const int slot = tid + it * 256;
        const int row  = slot >> 7;
        const int q    = slot & 127;
        const int gh   = h0 - 1 + row;
        f4 v = {0.f, 0.f, 0.f, 0.f};
        if ((unsigned)gh < (unsigned)Hh) {
            const float* p = xb + (size_t)gh * Ww + q * 4;
            v = *(const f4*)(p) + *(const f4*)(p + plane) + *(const f4*)(p + 2 * plane);
        }
        *(f4*)&sm[row][q * 4] = v;
    }

    float wx2[Kb], wy2[Kb];
#pragma unroll
    for (int k = 0; k < Kb; ++k) {
        wx2[k] = orient_w[2 * k]     * LOG2E_F;
        wy2[k] = orient_w[2 * k + 1] * LOG2E_F;
    }

    __syncthreads();

    const int cb = tx * 4;
    const int s0 = ty * 8;

    auto load_row = [&](int sr) -> RowW {
        const f4 m = *(const f4*)&sm[sr][cb];
        float L  = __shfl_up(m.w, 1);
        float Rr = __shfl_down(m.x, 1);
        if (lane == 0)  L  = (tx == 0)   ? 0.f : sm[sr][cb - 1];
        if (lane == 63) Rr = (tx == 127) ? 0.f : sm[sr][cb + 4];
        RowW r;
        r.hd[0] = m.y - L;   r.hd[1] = m.z - m.x;
        r.hd[2] = m.w - m.y; r.hd[3] = Rr - m.z;
        r.hs[0] = fmaf(2.f, m.x, L + m.y);
        r.hs[1] = fmaf(2.f, m.y, m.x + m.z);
        r.hs[2] = fmaf(2.f, m.z, m.y + m.w);
        r.hs[3] = fmaf(2.f, m.w, m.z + Rr);
        return r;
    };

    // ================= PHASE A: accumulate stats =================
    float accs[Kb], accq[Kb];
#pragma unroll
    for (int k = 0; k < Kb; ++k) { accs[k] = 0.f; accq[k] = 0.f; }

    auto acc_row = [&](const RowW& T, const RowW& M, const RowW& Bo) {
#pragma unroll
        for (int j = 0; j < 4; ++j) {
            const float gx = fmaf(2.f, M.hd[j], T.hd[j] + Bo.hd[j]);
            const float gy = Bo.hs[j] - T.hs[j];
            const float m2   = fmaf(gx, gx, fmaf(gy, gy, EPS_MAG_F));
            const float mag  = SQRTF(m2);
            const float mag2 = mag * LOG2E_F;
            float e[Kb], se = 0.f;
#pragma unroll
            for (int k = 0; k < Kb; ++k) {
                e[k] = EXP2F(fmaf(gx, wx2[k], fmaf(gy, wy2[k], -mag2)));
                se += e[k];
            }
            const float minv = mag * RCPF(se);
#pragma unroll
            for (int k = 0; k < Kb; ++k) {
                const float bv = e[k] * minv;
                accs[k] += bv;
                accq[k] = fmaf(bv, bv, accq[k]);
            }
        }
    };

    {
        RowW A  = load_row(s0);
        RowW Bf = load_row(s0 + 1);
        RowW Cf = load_row(s0 + 2); acc_row(A,  Bf, Cf);
        A  = load_row(s0 + 3);      acc_row(Bf, Cf, A);
        Bf = load_row(s0 + 4);      acc_row(Cf, A,  Bf);
        Cf = load_row(s0 + 5);      acc_row(A,  Bf, Cf);
        A  = load_row(s0 + 6);      acc_row(Bf, Cf, A);
        Bf = load_row(s0 + 7);      acc_row(Cf, A,  Bf);
        Cf = load_row(s0 + 8);      acc_row(A,  Bf, Cf);
        A  = load_row(s0 + 9);      acc_row(Bf, Cf, A);
    }

#pragma unroll
    for (int k = 0; k < Kb; ++k) {
        for (int off = 32; off > 0; off >>= 1) {
            accs[k] += __shfl_down(accs[k], off);
            accq[k] += __shfl_down(accq[k], off);
        }
    }
    const int wid = tid >> 6;
    if (lane == 0) {
#pragma unroll
        for (int k = 0; k < Kb; ++k) {
            red2[wid * 18 + k]     = accs[k];
            red2[wid * 18 + 9 + k] = accq[k];
        }
    }
    __syncthreads();
    if (tid < 18) {
        const float v = red2[tid] + red2[18 + tid] + red2[36 + tid] + red2[54 + tid];
        partial[((size_t)b * FCHUNKS + chunk) * 18 + tid] = v;
    }
    __threadfence();

    // ================= GRID SYNC =================
    cg::this_grid().sync();
    __threadfence();

    // ================= PHASE B: stats + output =================
    for (int idx = tid; idx < FCHUNKS * 18; idx += 256)
        red2[idx] = partial[(size_t)b * (FCHUNKS * 18) + idx];
    __syncthreads();
    if (tid < 18) {
        float s = 0.f;
#pragma unroll
        for (int blk = 0; blk < FCHUNKS; ++blk) s += red2[blk * 18 + tid];
        sums[tid] = s;
    }
    __syncthreads();
    if (tid < Kb) {
        const float invN = 1.f / (float)(Hh * Ww);
        const float mean = sums[tid] * invN;
        const float var  = fmaxf(sums[9 + tid] * invN - mean * mean, 0.f);
        const float rstd = rsqrtf(var + EPS_IN_F);
        const float sc   = rstd * gamma[tid];
        stsh[tid] = make_float2(sc, beta[tid] - mean * sc);
    }
    __syncthreads();

    float2 st[Kb];
#pragma unroll
    for (int k = 0; k < Kb; ++k) st[k] = stsh[k];

    auto out_row = [&](const RowW& T, const RowW& M, const RowW& Bo, int rr) {
        float ov[Kb][4];
#pragma unroll
        for (int j = 0; j < 4; ++j) {
            const float gx = fmaf(2.f, M.hd[j], T.hd[j] + Bo.hd[j]);
            const float gy = Bo.hs[j] - T.hs[j];
            const float m2   = fmaf(gx, gx, fmaf(gy, gy, EPS_MAG_F));
            const float mag  = SQRTF(m2);
            const float mag2 = mag * LOG2E_F;
            float e[Kb], se = 0.f;
#pragma unroll
            for (int k = 0; k < Kb; ++k) {
                e[k] = EXP2F(fmaf(gx, wx2[k], fmaf(gy, wy2[k], -mag2)));
                se += e[k];
            }
            const float minv = mag * RCPF(se);
#pragma unroll
            for (int k = 0; k < Kb; ++k) {
                ov[k][j] = fmaf(e[k] * minv, st[k].x, st[k].y);
            }
        }
        const int r_img = h0 + ty * 8 + rr;
        const size_t ob = ((size_t)(b * Kb) * Hh + r_img) * Ww + cb;
#pragma unroll
        for (int k = 0; k < Kb; ++k) {
            f4 v4 = {ov[k][0], ov[k][1], ov[k][2], ov[k][3]};
            __builtin_nontemporal_store(v4, (f4*)&out[ob + (size_t)k * plane]);
        }
    };

    {
        RowW A  = load_row(s0);
        RowW Bf = load_row(s0 + 1);
        RowW Cf = load_row(s0 + 2); out_row(A,  Bf, Cf, 0);
        A  = load_row(s0 + 3);      out_row(Bf, Cf, A,  1);
        Bf = load_row(s0 + 4);      out_row(Cf, A,  Bf, 2);
        Cf = load_row(s0 + 5);      out_row(A,  Bf, Cf, 3);
        A  = load_row(s0 + 6);      out_row(Bf, Cf, A,  4);
        Bf = load_row(s0 + 7);      out_row(Cf, A,  Bf, 5);
        Cf = load_row(s0 + 8);      out_row(A,  Bf, Cf, 6);
        A  = load_row(s0 + 9);      out_row(Bf, Cf, A,  7);
    }
}

// ============================================================================
// FALLBACK: proven R5 three-kernel pipeline (sidecar + stats + output)
// ============================================================================
constexpr int STH    = 8;
constexpr int SLDS_W = Ww + 8;    // 520
constexpr int SLDS_H = STH + 2;   // 10
constexpr int SCHUNKS = Hh / STH; // 64
constexpr int SNSLOT  = SLDS_H * (SLDS_W / 4); // 1300

template <int PASS>
__global__ __launch_bounds__(256) void goe_split_kernel(
    const float* __restrict__ x,
    const float* __restrict__ s_in,
    float* __restrict__ s_out,
    const float* __restrict__ orient_w,
    const float2* __restrict__ stats,
    float* __restrict__ partial,
    float* __restrict__ out)
{
    __shared__ float sm[SLDS_H][SLDS_W];

    const int b  = blockIdx.y;
    const int h0 = blockIdx.x * STH;
    const int tx = threadIdx.x;          // 0..127
    const int ty = threadIdx.y;          // 0..1
    const int tid = ty * 128 + tx;
    const int lane = tid & 63;

    const size_t plane = (size_t)Hh * Ww;
    const float* xb = x + (size_t)b * 3 * plane;

#pragma unroll
    for (int it = 0; it < 6; ++it) {
        const int slot = tid + it * 256;
        if (slot < SNSLOT) {
            const int row = slot / 130;
            const int q   = slot - row * 130;
            const int gh  = h0 - 1 + row;
            const int gw  = q * 4 - 4;
            const bool ok = (unsigned)gh < (unsigned)Hh && (unsigned)gw < (unsigned)Ww;
            f4 v = {0.f, 0.f, 0.f, 0.f};
            if (PASS == 0) {
                if (ok) {
                    const float* p = xb + (size_t)gh * Ww + gw;
                    v = *(const f4*)(p) + *(const f4*)(p + plane) + *(const f4*)(p + 2 * plane);
                }
                *(f4*)&sm[row][q * 4] = v;
                if ((unsigned)(row - 1) < (unsigned)STH && (unsigned)(q - 1) < 128u) {
                    *(f4*)&s_out[((size_t)b * Hh + gh) * Ww + gw] = v;
                }
            } else {
                if (ok) v = *(const f4*)&s_in[((size_t)b * Hh + gh) * Ww + gw];
                *(f4*)&sm[row][q * 4] = v;
            }
        }
    }

    float wx2[Kb], wy2[Kb];
#pragma unroll
    for (int k = 0; k < Kb; ++k) {
        wx2[k] = orient_w[2 * k]     * LOG2E_F;
        wy2[k] = orient_w[2 * k + 1] * LOG2E_F;
    }

    float2 st[Kb];
    if (PASS == 1) {
#pragma unroll
        for (int k = 0; k < Kb; ++k) st[k] = stats[b * Kb + k];
    }

    float accs[Kb], accq[Kb];
    if (PASS == 0) {
#pragma unroll
        for (int k = 0; k < Kb; ++k) { accs[k] = 0.f; accq[k] = 0.f; }
    }

    __syncthreads();

    const int cb    = tx * 4;
    const int rbase = ty * 4;

    auto load_row = [&](int sr) -> RowW {
        const f4 m = *(const f4*)&sm[sr][cb + 4];
        float L  = __shfl_up(m.w, 1);
        float Rr = __shfl_down(m.x, 1);
        if (lane == 0)  L  = sm[sr][cb + 3];
        if (lane == 63) Rr = sm[sr][cb + 8];
        RowW r;
        r.hd[0] = m.y - L;   r.hd[1] = m.z - m.x;
        r.hd[2] = m.w - m.y; r.hd[3] = Rr - m.z;
        r.hs[0] = fmaf(2.f, m.x, L + m.y);
        r.hs[1] = fmaf(2.f, m.y, m.x + m.z);
        r.hs[2] = fmaf(2.f, m.z, m.y + m.w);
        r.hs[3] = fmaf(2.f, m.w, m.z + Rr);
        return r;
    };

    auto do_row = [&](const RowW& T, const RowW& M, const RowW& Bo, int rr) {
        float ov[Kb][4];
#pragma unroll
        for (int j = 0; j < 4; ++j) {
            const float gx = fmaf(2.f, M.hd[j], T.hd[j] + Bo.hd[j]);
            const float gy = Bo.hs[j] - T.hs[j];
            const float m2   = fmaf(gx, gx, fmaf(gy, gy, EPS_MAG_F));
            const float mag  = SQRTF(m2);
            const float mag2 = mag * LOG2E_F;
            float e[Kb], se = 0.f;
#pragma unroll
            for (int k = 0; k < Kb; ++k) {
                e[k] = EXP2F(fmaf(gx, wx2[k], fmaf(gy, wy2[k], -mag2)));
                se += e[k];
            }
            const float minv = mag * RCPF(se);
#pragma unroll
            for (int k = 0; k < Kb; ++k) {
                const float bv = e[k] * minv;
                if (PASS == 0) {
                    accs[k] += bv;
                    accq[k] = fmaf(bv, bv, accq[k]);
                } else {
                    ov[k][j] = fmaf(bv, st[k].x, st[k].y);
                }
            }
        }
        if (PASS == 1) {
            const size_t ob = ((size_t)(b * Kb) * Hh + (h0 + rbase + rr)) * Ww + cb;
#pragma unroll
            for (int k = 0; k < Kb; ++k) {
                f4 v4 = {ov[k][0], ov[k][1], ov[k][2], ov[k][3]};
                __builtin_nontemporal_store(v4, (f4*)&out[ob + (size_t)k * plane]);
            }
        }
    };

    RowW A  = load_row(rbase);
    RowW Bf = load_row(rbase + 1);
    RowW Cf = load_row(rbase + 2); do_row(A,  Bf, Cf, 0);
    A  = load_row(rbase + 3);      do_row(Bf, Cf, A,  1);
    Bf = load_row(rbase + 4);      do_row(Cf, A,  Bf, 2);
    Cf = load_row(rbase + 5);      do_row(A,  Bf, Cf, 3);

    if (PASS == 0) {
#pragma unroll
        for (int k = 0; k < Kb; ++k) {
            for (int off = 32; off > 0; off >>= 1) {
                accs[k] += __shfl_down(accs[k], off);
                accq[k] += __shfl_down(accq[k], off);
            }
        }
        __syncthreads();
        float* red = &sm[0][0];
        const int wid = tid >> 6, ln = tid & 63;
        if (ln == 0) {
#pragma unroll
            for (int k = 0; k < Kb; ++k) {
                red[wid * 18 + k]     = accs[k];
                red[wid * 18 + 9 + k] = accq[k];
            }
        }
        __syncthreads();
        if (tid < 18) {
            const float v = red[tid] + red[18 + tid] + red[36 + tid] + red[54 + tid];
            partial[((size_t)b * SCHUNKS + blockIdx.x) * 18 + tid] = v;
        }
    }
}

__global__ __launch_bounds__(64) void goe_stats_kernel(
    const float* __restrict__ partial,
    const float* __restrict__ gamma,
    const float* __restrict__ beta,
    float2* __restrict__ stats)
{
    const int idx = blockIdx.x;
    const int b = idx / Kb, k = idx % Kb;
    const int t = threadIdx.x;

    const float* p = partial + ((size_t)b * SCHUNKS + t) * 18;
    float s = p[k];
    float q = p[9 + k];
    for (int off = 32; off > 0; off >>= 1) {
        s += __shfl_down(s, off);
        q += __shfl_down(q, off);
    }
    if (t == 0) {
        const float invN = 1.f / (float)(Hh * Ww);
        const float mean = s * invN;
        const float var  = fmaxf(q * invN - mean * mean, 0.f);
        const float rstd = rsqrtf(var + EPS_IN_F);
        const float sc   = rstd * gamma[k];
        stats[idx] = make_float2(sc, beta[k] - mean * sc);
    }
}

extern "C" void kernel_launch(void* const* d_in, const int* in_sizes, int n_in,
                              void* d_out, int out_size, void* d_ws, size_t ws_size,
                              hipStream_t stream)
{
    const float* x        = (const float*)d_in[0];
    const float* orient_w = (const float*)d_in[3];
    const float* gamma    = (const float*)d_in[4];
    const float* beta     = (const float*)d_in[5];
    float* outp = (float*)d_out;

    // Fused-path scratch: partial [32*32*18] at ws+0.
    float* fpartial = (float*)d_ws;

    void* args[] = {(void*)&x, (void*)&orient_w, (void*)&gamma, (void*)&beta,
                    (void*)&fpartial, (void*)&outp};
    hipError_t err = hipLaunchCooperativeKernel((void*)goe_fused_kernel,
                                                dim3(Bn * FCHUNKS), dim3(256),
                                                args, 0, stream);
    if (err == hipSuccess) return;
    (void)hipGetLastError();   // clear sticky error; take the proven 3-kernel path

    // Fallback scratch layout: sidecar [32*512*512 f32] | partial | stats
    float*  s_ws    = (float*)d_ws;
    float*  partial = (float*)((char*)d_ws + (size_t)Bn * Hh * Ww * sizeof(float));
    float2* stats   = (float2*)((char*)partial +
                       (size_t)Bn * SCHUNKS * 18 * sizeof(float));

    const dim3 grid(SCHUNKS, Bn);
    const dim3 block(128, 2);

    hipLaunchKernelGGL((goe_split_kernel<0>), grid, block, 0, stream,
                       x, nullptr, s_ws, orient_w, nullptr, partial, nullptr);
    hipLaunchKernelGGL(goe_stats_kernel, dim3(Bn * Kb), dim3(64), 0, stream,
                       partial, gamma, beta, stats);
    hipLaunchKernelGGL((goe_split_kernel<1>), grid, block, 0, stream,
                       nullptr, s_ws, nullptr, orient_w, stats, nullptr, outp);
}

// Round 8
// 132.080 us; speedup vs baseline: 2.0244x; 2.0244x over previous
//
#include <hip/hip_runtime.h>
#include <cstdint>
#include <cstddef>

typedef float f4 __attribute__((ext_vector_type(4)));

// Problem constants (match reference setup_inputs)
constexpr int Bn  = 32;
constexpr int Hh  = 512;
constexpr int Ww  = 512;
constexpr int Kb  = 9;
constexpr float EPS_MAG_F = 1e-6f;
constexpr float EPS_IN_F  = 1e-5f;
constexpr float LOG2E_F   = 1.4426950408889634f;

#if __has_builtin(__builtin_amdgcn_exp2f)
#define EXP2F(x) __builtin_amdgcn_exp2f(x)
#else
#define EXP2F(x) exp2f(x)
#endif
#if __has_builtin(__builtin_amdgcn_sqrtf)
#define SQRTF(x) __builtin_amdgcn_sqrtf(x)
#else
#define SQRTF(x) sqrtf(x)
#endif
#if __has_builtin(__builtin_amdgcn_rcpf)
#define RCPF(x) __builtin_amdgcn_rcpf(x)
#else
#define RCPF(x) (1.0f / (x))
#endif

struct RowW { float hd[4]; float hs[4]; };

// ============================================================================
// FUSED kernel (cooperative launch for co-residency; per-image sleep-sync).
// 1024 blocks (32 img x 32 chunks), 256 thr, 4/CU, LDS tile resident across
// the sync. Phase A: stage channel-summed 18x512 tile, per-block partials.
// Per-image counter sync (s_sleep poll). Phase B: redundant deterministic
// stats reduce, recompute from resident LDS, NT-write output.
// ============================================================================
constexpr int FTH     = 16;
constexpr int FCHUNKS = Hh / FTH;            // 32
constexpr int FLDS_H  = FTH + 2;             // 18
constexpr int CNT_STRIDE_U32 = 16;           // 64 B per image counter

__global__ __launch_bounds__(256, 4) void goe_fused_kernel(
    const float* __restrict__ x,         // [B,3,H,W]
    const float* __restrict__ orient_w,  // [9,2]
    const float* __restrict__ gamma,     // [9]
    const float* __restrict__ beta,      // [9]
    unsigned int* __restrict__ cnt,      // [32 * 16] zeroed per launch
    float* __restrict__ partial,         // [32*32*18]
    float* __restrict__ out)             // [B,9,H,W]
{
    __shared__ float sm[FLDS_H][Ww];     // 36.9 KB, persists across sync
    __shared__ float red2[FCHUNKS * 18]; // 2.3 KB
    __shared__ float sums[18];
    __shared__ float2 stsh[Kb];

    const int bx    = blockIdx.x;
    const int b     = bx >> 5;           // /FCHUNKS
    const int chunk = bx & (FCHUNKS - 1);
    const int h0    = chunk * FTH;
    const int tid   = threadIdx.x;       // 0..255
    const int tx    = tid & 127;
    const int ty    = tid >> 7;
    const int lane  = tid & 63;

    const size_t plane = (size_t)Hh * Ww;
    const float* xb = x + (size_t)b * 3 * plane;

    // ---- stage channel-summed 18x512 tile (zero-padded top/bottom rows) ----
#pragma unroll
    for (int it = 0; it < 9; ++it) {
        const int slot = tid + it * 256;
        const int row  = slot >> 7;
        const int q    = slot & 127;
        const int gh   = h0 - 1 + row;
        f4 v = {0.f, 0.f, 0.f, 0.f};
        if ((unsigned)gh < (unsigned)Hh) {
            const float* p = xb + (size_t)gh * Ww + q * 4;
            v = *(const f4*)(p) + *(const f4*)(p + plane) + *(const f4*)(p + 2 * plane);
        }
        *(f4*)&sm[row][q * 4] = v;
    }

    float wx2[Kb], wy2[Kb];
#pragma unroll
    for (int k = 0; k < Kb; ++k) {
        wx2[k] = orient_w[2 * k]     * LOG2E_F;
        wy2[k] = orient_w[2 * k + 1] * LOG2E_F;
    }

    __syncthreads();

    const int cb = tx * 4;
    const int s0 = ty * 8;

    auto load_row = [&](int sr) -> RowW {
        const f4 m = *(const f4*)&sm[sr][cb];
        float L  = __shfl_up(m.w, 1);
        float Rr = __shfl_down(m.x, 1);
        if (lane == 0)  L  = (tx == 0)   ? 0.f : sm[sr][cb - 1];
        if (lane == 63) Rr = (tx == 127) ? 0.f : sm[sr][cb + 4];
        RowW r;
        r.hd[0] = m.y - L;   r.hd[1] = m.z - m.x;
        r.hd[2] = m.w - m.y; r.hd[3] = Rr - m.z;
        r.hs[0] = fmaf(2.f, m.x, L + m.y);
        r.hs[1] = fmaf(2.f, m.y, m.x + m.z);
        r.hs[2] = fmaf(2.f, m.z, m.y + m.w);
        r.hs[3] = fmaf(2.f, m.w, m.z + Rr);
        return r;
    };

    // ================= PHASE A: accumulate stats =================
    float accs[Kb], accq[Kb];
#pragma unroll
    for (int k = 0; k < Kb; ++k) { accs[k] = 0.f; accq[k] = 0.f; }

    auto acc_row = [&](const RowW& T, const RowW& M, const RowW& Bo) {
#pragma unroll
        for (int j = 0; j < 4; ++j) {
            const float gx = fmaf(2.f, M.hd[j], T.hd[j] + Bo.hd[j]);
            const float gy = Bo.hs[j] - T.hs[j];
            const float m2   = fmaf(gx, gx, fmaf(gy, gy, EPS_MAG_F));
            const float mag  = SQRTF(m2);
            const float mag2 = mag * LOG2E_F;
            float e[Kb], se = 0.f;
#pragma unroll
            for (int k = 0; k < Kb; ++k) {
                e[k] = EXP2F(fmaf(gx, wx2[k], fmaf(gy, wy2[k], -mag2)));
                se += e[k];
            }
            const float minv = mag * RCPF(se);
#pragma unroll
            for (int k = 0; k < Kb; ++k) {
                const float bv = e[k] * minv;
                accs[k] += bv;
                accq[k] = fmaf(bv, bv, accq[k]);
            }
        }
    };

    {
        RowW A  = load_row(s0);
        RowW Bf = load_row(s0 + 1);
        RowW Cf = load_row(s0 + 2); acc_row(A,  Bf, Cf);
        A  = load_row(s0 + 3);      acc_row(Bf, Cf, A);
        Bf = load_row(s0 + 4);      acc_row(Cf, A,  Bf);
        Cf = load_row(s0 + 5);      acc_row(A,  Bf, Cf);
        A  = load_row(s0 + 6);      acc_row(Bf, Cf, A);
        Bf = load_row(s0 + 7);      acc_row(Cf, A,  Bf);
        Cf = load_row(s0 + 8);      acc_row(A,  Bf, Cf);
        A  = load_row(s0 + 9);      acc_row(Bf, Cf, A);
    }

#pragma unroll
    for (int k = 0; k < Kb; ++k) {
        for (int off = 32; off > 0; off >>= 1) {
            accs[k] += __shfl_down(accs[k], off);
            accq[k] += __shfl_down(accq[k], off);
        }
    }
    const int wid = tid >> 6;
    if (lane == 0) {
#pragma unroll
        for (int k = 0; k < Kb; ++k) {
            red2[wid * 18 + k]     = accs[k];
            red2[wid * 18 + 9 + k] = accq[k];
        }
    }
    __syncthreads();
    if (tid < 18) {
        const float v = red2[tid] + red2[18 + tid] + red2[36 + tid] + red2[54 + tid];
        // agent-scope store: visible at coherent point, immune to XCD L2 staleness
        __hip_atomic_store(&partial[((size_t)b * FCHUNKS + chunk) * 18 + tid], v,
                           __ATOMIC_RELAXED, __HIP_MEMORY_SCOPE_AGENT);
    }
    __syncthreads();

    // ================= PER-IMAGE SYNC (sleep-poll) =================
    if (tid == 0) {
        __hip_atomic_fetch_add(&cnt[b * CNT_STRIDE_U32], 1u,
                               __ATOMIC_RELEASE, __HIP_MEMORY_SCOPE_AGENT);
        while (__hip_atomic_load(&cnt[b * CNT_STRIDE_U32],
                                 __ATOMIC_RELAXED, __HIP_MEMORY_SCOPE_AGENT)
               < (unsigned)FCHUNKS)
            __builtin_amdgcn_s_sleep(32);
        __builtin_amdgcn_fence(__ATOMIC_ACQUIRE, "agent");
    }
    __syncthreads();

    // ================= PHASE B: stats + output =================
    for (int idx = tid; idx < FCHUNKS * 18; idx += 256)
        red2[idx] = __hip_atomic_load(&partial[(size_t)b * (FCHUNKS * 18) + idx],
                                      __ATOMIC_RELAXED, __HIP_MEMORY_SCOPE_AGENT);
    __syncthreads();
    if (tid < 18) {
        float s = 0.f;
#pragma unroll
        for (int blk = 0; blk < FCHUNKS; ++blk) s += red2[blk * 18 + tid];
        sums[tid] = s;
    }
    __syncthreads();
    if (tid < Kb) {
        const float invN = 1.f / (float)(Hh * Ww);
        const float mean = sums[tid] * invN;
        const float var  = fmaxf(sums[9 + tid] * invN - mean * mean, 0.f);
        const float rstd = rsqrtf(var + EPS_IN_F);
        const float sc   = rstd * gamma[tid];
        stsh[tid] = make_float2(sc, beta[tid] - mean * sc);
    }
    __syncthreads();

    float2 st[Kb];
#pragma unroll
    for (int k = 0; k < Kb; ++k) st[k] = stsh[k];

    auto out_row = [&](const RowW& T, const RowW& M, const RowW& Bo, int rr) {
        float ov[Kb][4];
#pragma unroll
        for (int j = 0; j < 4; ++j) {
            const float gx = fmaf(2.f, M.hd[j], T.hd[j] + Bo.hd[j]);
            const float gy = Bo.hs[j] - T.hs[j];
            const float m2   = fmaf(gx, gx, fmaf(gy, gy, EPS_MAG_F));
            const float mag  = SQRTF(m2);
            const float mag2 = mag * LOG2E_F;
            float e[Kb], se = 0.f;
#pragma unroll
            for (int k = 0; k < Kb; ++k) {
                e[k] = EXP2F(fmaf(gx, wx2[k], fmaf(gy, wy2[k], -mag2)));
                se += e[k];
            }
            const float minv = mag * RCPF(se);
#pragma unroll
            for (int k = 0; k < Kb; ++k) {
                ov[k][j] = fmaf(e[k] * minv, st[k].x, st[k].y);
            }
        }
        const int r_img = h0 + ty * 8 + rr;
        const size_t ob = ((size_t)(b * Kb) * Hh + r_img) * Ww + cb;
#pragma unroll
        for (int k = 0; k < Kb; ++k) {
            f4 v4 = {ov[k][0], ov[k][1], ov[k][2], ov[k][3]};
            __builtin_nontemporal_store(v4, (f4*)&out[ob + (size_t)k * plane]);
        }
    };

    {
        RowW A  = load_row(s0);
        RowW Bf = load_row(s0 + 1);
        RowW Cf = load_row(s0 + 2); out_row(A,  Bf, Cf, 0);
        A  = load_row(s0 + 3);      out_row(Bf, Cf, A,  1);
        Bf = load_row(s0 + 4);      out_row(Cf, A,  Bf, 2);
        Cf = load_row(s0 + 5);      out_row(A,  Bf, Cf, 3);
        A  = load_row(s0 + 6);      out_row(Bf, Cf, A,  4);
        Bf = load_row(s0 + 7);      out_row(Cf, A,  Bf, 5);
        Cf = load_row(s0 + 8);      out_row(A,  Bf, Cf, 6);
        A  = load_row(s0 + 9);      out_row(Bf, Cf, A,  7);
    }
}

// ============================================================================
// FALLBACK: proven R5 three-kernel pipeline (sidecar + stats + output)
// ============================================================================
constexpr int STH    = 8;
constexpr int SLDS_W = Ww + 8;    // 520
constexpr int SLDS_H = STH + 2;   // 10
constexpr int SCHUNKS = Hh / STH; // 64
constexpr int SNSLOT  = SLDS_H * (SLDS_W / 4); // 1300

template <int PASS>
__global__ __launch_bounds__(256) void goe_split_kernel(
    const float* __restrict__ x,
    const float* __restrict__ s_in,
    float* __restrict__ s_out,
    const float* __restrict__ orient_w,
    const float2* __restrict__ stats,
    float* __restrict__ partial,
    float* __restrict__ out)
{
    __shared__ float sm[SLDS_H][SLDS_W];

    const int b  = blockIdx.y;
    const int h0 = blockIdx.x * STH;
    const int tx = threadIdx.x;          // 0..127
    const int ty = threadIdx.y;          // 0..1
    const int tid = ty * 128 + tx;
    const int lane = tid & 63;

    const size_t plane = (size_t)Hh * Ww;
    const float* xb = x + (size_t)b * 3 * plane;

#pragma unroll
    for (int it = 0; it < 6; ++it) {
        const int slot = tid + it * 256;
        if (slot < SNSLOT) {
            const int row = slot / 130;
            const int q   = slot - row * 130;
            const int gh  = h0 - 1 + row;
            const int gw  = q * 4 - 4;
            const bool ok = (unsigned)gh < (unsigned)Hh && (unsigned)gw < (unsigned)Ww;
            f4 v = {0.f, 0.f, 0.f, 0.f};
            if (PASS == 0) {
                if (ok) {
                    const float* p = xb + (size_t)gh * Ww + gw;
                    v = *(const f4*)(p) + *(const f4*)(p + plane) + *(const f4*)(p + 2 * plane);
                }
                *(f4*)&sm[row][q * 4] = v;
                if ((unsigned)(row - 1) < (unsigned)STH && (unsigned)(q - 1) < 128u) {
                    *(f4*)&s_out[((size_t)b * Hh + gh) * Ww + gw] = v;
                }
            } else {
                if (ok) v = *(const f4*)&s_in[((size_t)b * Hh + gh) * Ww + gw];
                *(f4*)&sm[row][q * 4] = v;
            }
        }
    }

    float wx2[Kb], wy2[Kb];
#pragma unroll
    for (int k = 0; k < Kb; ++k) {
        wx2[k] = orient_w[2 * k]     * LOG2E_F;
        wy2[k] = orient_w[2 * k + 1] * LOG2E_F;
    }

    float2 st[Kb];
    if (PASS == 1) {
#pragma unroll
        for (int k = 0; k < Kb; ++k) st[k] = stats[b * Kb + k];
    }

    float accs[Kb], accq[Kb];
    if (PASS == 0) {
#pragma unroll
        for (int k = 0; k < Kb; ++k) { accs[k] = 0.f; accq[k] = 0.f; }
    }

    __syncthreads();

    const int cb    = tx * 4;
    const int rbase = ty * 4;

    auto load_row = [&](int sr) -> RowW {
        const f4 m = *(const f4*)&sm[sr][cb + 4];
        float L  = __shfl_up(m.w, 1);
        float Rr = __shfl_down(m.x, 1);
        if (lane == 0)  L  = sm[sr][cb + 3];
        if (lane == 63) Rr = sm[sr][cb + 8];
        RowW r;
        r.hd[0] = m.y - L;   r.hd[1] = m.z - m.x;
        r.hd[2] = m.w - m.y; r.hd[3] = Rr - m.z;
        r.hs[0] = fmaf(2.f, m.x, L + m.y);
        r.hs[1] = fmaf(2.f, m.y, m.x + m.z);
        r.hs[2] = fmaf(2.f, m.z, m.y + m.w);
        r.hs[3] = fmaf(2.f, m.w, m.z + Rr);
        return r;
    };

    auto do_row = [&](const RowW& T, const RowW& M, const RowW& Bo, int rr) {
        float ov[Kb][4];
#pragma unroll
        for (int j = 0; j < 4; ++j) {
            const float gx = fmaf(2.f, M.hd[j], T.hd[j] + Bo.hd[j]);
            const float gy = Bo.hs[j] - T.hs[j];
            const float m2   = fmaf(gx, gx, fmaf(gy, gy, EPS_MAG_F));
            const float mag  = SQRTF(m2);
            const float mag2 = mag * LOG2E_F;
            float e[Kb], se = 0.f;
#pragma unroll
            for (int k = 0; k < Kb; ++k) {
                e[k] = EXP2F(fmaf(gx, wx2[k], fmaf(gy, wy2[k], -mag2)));
                se += e[k];
            }
            const float minv = mag * RCPF(se);
#pragma unroll
            for (int k = 0; k < Kb; ++k) {
                const float bv = e[k] * minv;
                if (PASS == 0) {
                    accs[k] += bv;
                    accq[k] = fmaf(bv, bv, accq[k]);
                } else {
                    ov[k][j] = fmaf(bv, st[k].x, st[k].y);
                }
            }
        }
        if (PASS == 1) {
            const size_t ob = ((size_t)(b * Kb) * Hh + (h0 + rbase + rr)) * Ww + cb;
#pragma unroll
            for (int k = 0; k < Kb; ++k) {
                f4 v4 = {ov[k][0], ov[k][1], ov[k][2], ov[k][3]};
                __builtin_nontemporal_store(v4, (f4*)&out[ob + (size_t)k * plane]);
            }
        }
    };

    RowW A  = load_row(rbase);
    RowW Bf = load_row(rbase + 1);
    RowW Cf = load_row(rbase + 2); do_row(A,  Bf, Cf, 0);
    A  = load_row(rbase + 3);      do_row(Bf, Cf, A,  1);
    Bf = load_row(rbase + 4);      do_row(Cf, A,  Bf, 2);
    Cf = load_row(rbase + 5);      do_row(A,  Bf, Cf, 3);

    if (PASS == 0) {
#pragma unroll
        for (int k = 0; k < Kb; ++k) {
            for (int off = 32; off > 0; off >>= 1) {
                accs[k] += __shfl_down(accs[k], off);
                accq[k] += __shfl_down(accq[k], off);
            }
        }
        __syncthreads();
        float* red = &sm[0][0];
        const int wid = tid >> 6, ln = tid & 63;
        if (ln == 0) {
#pragma unroll
            for (int k = 0; k < Kb; ++k) {
                red[wid * 18 + k]     = accs[k];
                red[wid * 18 + 9 + k] = accq[k];
            }
        }
        __syncthreads();
        if (tid < 18) {
            const float v = red[tid] + red[18 + tid] + red[36 + tid] + red[54 + tid];
            partial[((size_t)b * SCHUNKS + blockIdx.x) * 18 + tid] = v;
        }
    }
}

__global__ __launch_bounds__(64) void goe_stats_kernel(
    const float* __restrict__ partial,
    const float* __restrict__ gamma,
    const float* __restrict__ beta,
    float2* __restrict__ stats)
{
    const int idx = blockIdx.x;
    const int b = idx / Kb, k = idx % Kb;
    const int t = threadIdx.x;

    const float* p = partial + ((size_t)b * SCHUNKS + t) * 18;
    float s = p[k];
    float q = p[9 + k];
    for (int off = 32; off > 0; off >>= 1) {
        s += __shfl_down(s, off);
        q += __shfl_down(q, off);
    }
    if (t == 0) {
        const float invN = 1.f / (float)(Hh * Ww);
        const float mean = s * invN;
        const float var  = fmaxf(q * invN - mean * mean, 0.f);
        const float rstd = rsqrtf(var + EPS_IN_F);
        const float sc   = rstd * gamma[k];
        stats[idx] = make_float2(sc, beta[k] - mean * sc);
    }
}

extern "C" void kernel_launch(void* const* d_in, const int* in_sizes, int n_in,
                              void* d_out, int out_size, void* d_ws, size_t ws_size,
                              hipStream_t stream)
{
    const float* x        = (const float*)d_in[0];
    const float* orient_w = (const float*)d_in[3];
    const float* gamma    = (const float*)d_in[4];
    const float* beta     = (const float*)d_in[5];
    float* outp = (float*)d_out;

    // Fused-path scratch: [cnt 32*64B = 2048 B][partial 32*32*18 f32]
    unsigned int* cnt = (unsigned int*)d_ws;
    float* fpartial   = (float*)((char*)d_ws + 2048);

    // zero the sync counters every launch (captured in the graph -> replayed)
    (void)hipMemsetAsync(d_ws, 0, 2048, stream);

    void* args[] = {(void*)&x, (void*)&orient_w, (void*)&gamma, (void*)&beta,
                    (void*)&cnt, (void*)&fpartial, (void*)&outp};
    hipError_t err = hipLaunchCooperativeKernel((void*)goe_fused_kernel,
                                                dim3(Bn * FCHUNKS), dim3(256),
                                                args, 0, stream);
    if (err == hipSuccess) return;
    (void)hipGetLastError();   // clear sticky error; take the proven 3-kernel path

    // Fallback scratch layout: sidecar [32*512*512 f32] | partial | stats
    float*  s_ws    = (float*)d_ws;
    float*  partial = (float*)((char*)d_ws + (size_t)Bn * Hh * Ww * sizeof(float));
    float2* stats   = (float2*)((char*)partial +
                       (size_t)Bn * SCHUNKS * 18 * sizeof(float));

    const dim3 grid(SCHUNKS, Bn);
    const dim3 block(128, 2);

    hipLaunchKernelGGL((goe_split_kernel<0>), grid, block, 0, stream,
                       x, nullptr, s_ws, orient_w, nullptr, partial, nullptr);
    hipLaunchKernelGGL(goe_stats_kernel, dim3(Bn * Kb), dim3(64), 0, stream,
                       partial, gamma, beta, stats);
    hipLaunchKernelGGL((goe_split_kernel<1>), grid, block, 0, stream,
                       nullptr, s_ws, nullptr, orient_w, stats, nullptr, outp);
}